// Round 1
// baseline (188.047 us; speedup 1.0000x reference)
//
#include <hip/hip_runtime.h>
#include <hip/hip_bf16.h>

#define Bb 8
#define Nn 1024
#define Hh 12
#define C3 2304
#define SCALE 0.125f
#define QBLK 64
#define KVBLK 64
#define NT 29
#define NQT (Nn / QBLK)
#define NKT (Nn / KVBLK)

typedef short bf16x8 __attribute__((ext_vector_type(8)));
typedef float f32x4 __attribute__((ext_vector_type(4)));
typedef unsigned short u16t;

__device__ __forceinline__ float b2f(u16t v) {
    union { unsigned u; float f; } x; x.u = ((unsigned)v) << 16; return x.f;
}
__device__ __forceinline__ u16t f2b(float f) {
    union { float f; unsigned u; } x; x.f = f;
    unsigned r = x.u + 0x7fffu + ((x.u >> 16) & 1u);
    return (u16t)(r >> 16);
}
// swizzled element index for row-major [rows][64] bf16 tiles (128B rows)
__device__ __forceinline__ int swz(int row, int col) {
    return (row * 64 + col) ^ ((row & 7) << 3);
}

__global__ __launch_bounds__(256, 3) void attn_kernel(
        const float* __restrict__ x,
        const float* __restrict__ tk,
        const float* __restrict__ tv,
        float* __restrict__ out) {
    __shared__ __align__(16) char smem[47872];
    u16t* Qlds  = (u16t*)smem;             // 8KB  [64][64] bf16 swizzled
    u16t* Klds  = (u16t*)(smem + 8192);    // 8KB  [64 keys][64 d]
    u16t* Vtlds = (u16t*)(smem + 16384);   // 8KB  [64 d][64 keys]
    u16t* Plds  = (u16t*)(smem + 24576);   // 8KB  per-wave [16 q][64 keys]
    float* qrel  = (float*)(smem + 32768); // [64][29]
    float* wdiag = (float*)(smem + 40192); // [64][27]
    float* lowL  = (float*)(smem + 47104); // [64]
    float* highL = (float*)(smem + 47360); // [64]
    float* Linv  = (float*)(smem + 47616); // [64]
    float* out2f = (float*)smem;           // reuse Qlds+Klds (16KB) after kv loop

    const int tid = threadIdx.x;
    const int bid = blockIdx.x;
    const int qt = bid % NQT;
    const int h  = (bid / NQT) % Hh;
    const int b  = bid / (NQT * Hh);
    const int lane = tid & 63;
    const int w = tid >> 6;
    const int g = lane >> 4;
    const int c = lane & 15;
    const int q0 = qt * QBLK;
    const float* xb = x + (size_t)b * Nn * C3;

    for (int i = tid; i < QBLK * 27; i += 256) wdiag[i] = 0.f;

    // ---- stage Q tile as bf16 (swizzled) ----
    #pragma unroll
    for (int rep = 0; rep < 4; ++rep) {
        int idx = tid + rep * 256;
        int row = idx >> 4;
        int d0 = (idx & 15) * 4;
        float4 v4 = *(const float4*)&xb[(size_t)(q0 + row) * C3 + h * 64 + d0];
        ushort4 s4;
        s4.x = f2b(v4.x); s4.y = f2b(v4.y); s4.z = f2b(v4.z); s4.w = f2b(v4.w);
        *(ushort4*)&Qlds[swz(row, d0)] = s4;
    }
    __syncthreads();

    // ---- qrel[q][t] = Q[q,:] . tk[t,:] ----
    for (int pid = tid; pid < QBLK * NT; pid += 256) {
        int q = pid / NT;
        int t = pid - q * NT;
        float s = 0.f;
        #pragma unroll
        for (int d0 = 0; d0 < 64; d0 += 8) {
            bf16x8 qv = *(const bf16x8*)&Qlds[swz(q, d0)];
            float4 t0 = *(const float4*)&tk[t * 64 + d0];
            float4 t1 = *(const float4*)&tk[t * 64 + d0 + 4];
            s += b2f((u16t)qv[0]) * t0.x + b2f((u16t)qv[1]) * t0.y
               + b2f((u16t)qv[2]) * t0.z + b2f((u16t)qv[3]) * t0.w
               + b2f((u16t)qv[4]) * t1.x + b2f((u16t)qv[5]) * t1.y
               + b2f((u16t)qv[6]) * t1.z + b2f((u16t)qv[7]) * t1.w;
        }
        qrel[q * NT + t] = s;
    }
    __syncthreads();

    // ---- per-wave Q fragments (A-operand): row = c, k = k0*32 + g*8 ----
    bf16x8 qfrag0 = *(const bf16x8*)&Qlds[swz(w * 16 + c, g * 8)];
    bf16x8 qfrag1 = *(const bf16x8*)&Qlds[swz(w * 16 + c, 32 + g * 8)];

    float qrl0[4], qrl28[4];
    #pragma unroll
    for (int r = 0; r < 4; ++r) {
        int ql = w * 16 + g * 4 + r;
        qrl0[r]  = qrel[ql * NT + 0];
        qrl28[r] = qrel[ql * NT + 28];
    }

    f32x4 of[4] = {};
    float lowA[4] = {0.f, 0.f, 0.f, 0.f};
    float highA[4] = {0.f, 0.f, 0.f, 0.f};
    const int qg_base = q0 + w * 16;

    for (int kt = 0; kt < NKT; ++kt) {
        const int kv0 = kt * KVBLK;
        __syncthreads();   // previous tile's PV reads finished before overwrite
        // ---- stage K (row-major) and V (transposed) as bf16 ----
        #pragma unroll
        for (int rep = 0; rep < 4; ++rep) {
            int idx = tid + rep * 256;
            int m = idx >> 4;
            int d0 = (idx & 15) * 4;
            const float* src = &xb[(size_t)(kv0 + m) * C3 + 768 + h * 64 + d0];
            float4 kv4 = *(const float4*)src;
            ushort4 s4;
            s4.x = f2b(kv4.x); s4.y = f2b(kv4.y); s4.z = f2b(kv4.z); s4.w = f2b(kv4.w);
            *(ushort4*)&Klds[swz(m, d0)] = s4;
            float4 vv4 = *(const float4*)(src + 768);
            Vtlds[swz(d0 + 0, m)] = f2b(vv4.x);
            Vtlds[swz(d0 + 1, m)] = f2b(vv4.y);
            Vtlds[swz(d0 + 2, m)] = f2b(vv4.z);
            Vtlds[swz(d0 + 3, m)] = f2b(vv4.w);
        }
        __syncthreads();

        // ---- S = Q.K^T per 16-col subtile, exp + bucket, P to LDS ----
        #pragma unroll
        for (int ct = 0; ct < 4; ++ct) {
            f32x4 s = {};
            {
                bf16x8 kf0 = *(const bf16x8*)&Klds[swz(ct * 16 + c, g * 8)];
                s = __builtin_amdgcn_mfma_f32_16x16x32_bf16(qfrag0, kf0, s, 0, 0, 0);
                bf16x8 kf1 = *(const bf16x8*)&Klds[swz(ct * 16 + c, 32 + g * 8)];
                s = __builtin_amdgcn_mfma_f32_16x16x32_bf16(qfrag1, kf1, s, 0, 0, 0);
            }
            const int key_g = kv0 + ct * 16 + c;
            const int dmax = kv0 + ct * 16 + 15 - qg_base;
            const int dmin = kv0 + ct * 16 - (qg_base + 15);
            float e[4];
            if (dmax <= -14) {              // whole subtile in bucket 0
                #pragma unroll
                for (int r = 0; r < 4; ++r) {
                    e[r] = __expf((s[r] + qrl0[r]) * SCALE);
                    lowA[r] += e[r];
                }
            } else if (dmin >= 14) {        // whole subtile in bucket 28
                #pragma unroll
                for (int r = 0; r < 4; ++r) {
                    e[r] = __expf((s[r] + qrl28[r]) * SCALE);
                    highA[r] += e[r];
                }
            } else {                        // diagonal band: generic path
                #pragma unroll
                for (int r = 0; r < 4; ++r) {
                    int ql = w * 16 + g * 4 + r;
                    int qg = q0 + ql;
                    int delta = key_g - qg;
                    int t = delta + 14;
                    t = t < 0 ? 0 : (t > 28 ? 28 : t);
                    float bias = qrel[ql * NT + t];
                    e[r] = __expf((s[r] + bias) * SCALE);
                    if (delta <= -14)      lowA[r] += e[r];
                    else if (delta >= 14)  highA[r] += e[r];
                    else                   wdiag[ql * 27 + delta + 13] = e[r];
                }
            }
            #pragma unroll
            for (int r = 0; r < 4; ++r)
                Plds[w * 1024 + swz(g * 4 + r, ct * 16 + c)] = f2b(e[r]);
        }
        asm volatile("s_waitcnt lgkmcnt(0)" ::: "memory");  // P writes visible wave-wide

        // ---- O += P.V ----
        #pragma unroll
        for (int k0 = 0; k0 < 2; ++k0) {
            bf16x8 pf = *(const bf16x8*)&Plds[w * 1024 + swz(c, k0 * 32 + g * 8)];
            #pragma unroll
            for (int dt = 0; dt < 4; ++dt) {
                bf16x8 vf = *(const bf16x8*)&Vtlds[swz(dt * 16 + c, k0 * 32 + g * 8)];
                of[dt] = __builtin_amdgcn_mfma_f32_16x16x32_bf16(pf, vf, of[dt], 0, 0, 0);
            }
        }
    }

    // ---- reduce low/high over the 16 lanes of each row group ----
    #pragma unroll
    for (int r = 0; r < 4; ++r) {
        float lo = lowA[r], hi = highA[r];
        #pragma unroll
        for (int m = 1; m < 16; m <<= 1) {
            lo += __shfl_xor(lo, m, 64);
            hi += __shfl_xor(hi, m, 64);
        }
        if (c == 0) {
            lowL[w * 16 + g * 4 + r]  = lo;
            highL[w * 16 + g * 4 + r] = hi;
        }
    }
    __syncthreads();

    // ---- out2[q][d] = sum_t w[t]*tv[t][d]; L = sum_t w[t] ----
    {
        const int q = tid >> 2;
        const int dp = (tid & 3) * 16;
        float lo = lowL[q], hi = highL[q];
        float wsum = lo + hi;
        float acc[16];
        const float* tva = &tv[dp];
        const float* tvb = &tv[28 * 64 + dp];
        #pragma unroll
        for (int i = 0; i < 16; ++i) acc[i] = lo * tva[i] + hi * tvb[i];
        for (int t = 1; t <= 27; ++t) {
            float wv = wdiag[q * 27 + (t - 1)];
            wsum += wv;
            const float* tvr = &tv[t * 64 + dp];
            #pragma unroll
            for (int i = 0; i < 16; ++i) acc[i] = fmaf(wv, tvr[i], acc[i]);
        }
        #pragma unroll
        for (int i = 0; i < 16; ++i) out2f[q * 64 + dp + i] = acc[i];
        if ((tid & 3) == 0) Linv[q] = 1.f / wsum;
    }
    __syncthreads();

    // ---- epilogue: out = (O + out2) / L ----
    #pragma unroll
    for (int dt = 0; dt < 4; ++dt) {
        #pragma unroll
        for (int r = 0; r < 4; ++r) {
            int ql = w * 16 + g * 4 + r;
            int d = dt * 16 + c;
            float val = (of[dt][r] + out2f[ql * 64 + d]) * Linv[ql];
            out[((size_t)b * Nn + q0 + ql) * 768 + h * 64 + d] = val;
        }
    }
}

extern "C" void kernel_launch(void* const* d_in, const int* in_sizes, int n_in,
                              void* d_out, int out_size, void* d_ws, size_t ws_size,
                              hipStream_t stream) {
    const float* x  = (const float*)d_in[0];
    const float* tk = (const float*)d_in[1];
    const float* tv = (const float*)d_in[2];
    float* out = (float*)d_out;
    attn_kernel<<<dim3(Bb * Hh * NQT), dim3(256), 0, stream>>>(x, tk, tv, out);
}

// Round 2
// 170.760 us; speedup vs baseline: 1.1012x; 1.1012x over previous
//
#include <hip/hip_runtime.h>
#include <hip/hip_bf16.h>

#define Bb 8
#define Nn 1024
#define Hh 12
#define C3 2304
#define SCALE 0.125f
#define QBLK 64
#define KVBLK 64
#define NT 29
#define NQT (Nn / QBLK)
#define NKT (Nn / KVBLK)
#define TILE_ELEMS 4096   // 64x64 bf16 tile

typedef short bf16x8 __attribute__((ext_vector_type(8)));
typedef float f32x4 __attribute__((ext_vector_type(4)));
typedef unsigned short u16t;

__device__ __forceinline__ float b2f(u16t v) {
    union { unsigned u; float f; } x; x.u = ((unsigned)v) << 16; return x.f;
}
__device__ __forceinline__ u16t f2b(float f) {
    union { float f; unsigned u; } x; x.f = f;
    unsigned r = x.u + 0x7fffu + ((x.u >> 16) & 1u);
    return (u16t)(r >> 16);
}
// swizzled element index for row-major [rows][64] bf16 tiles (128B rows)
__device__ __forceinline__ int swz(int row, int col) {
    return (row * 64 + col) ^ ((row & 7) << 3);
}
// async global->LDS, 16B per lane; LDS dest is wave-uniform base (+lane*16 by HW)
__device__ __forceinline__ void gl_lds16(const void* g, void* l) {
    __builtin_amdgcn_global_load_lds(
        (const __attribute__((address_space(1))) unsigned int*)g,
        (__attribute__((address_space(3))) unsigned int*)l, 16, 0, 0);
}

// ---------------- pass 1: fp32 -> bf16, pre-swizzled K tiles + transposed V tiles ----
__global__ __launch_bounds__(256) void preconv_kernel(
        const float* __restrict__ x, u16t* __restrict__ wsK, u16t* __restrict__ wsV) {
    __shared__ __align__(16) u16t Vt[TILE_ELEMS];
    const int bid = blockIdx.x;                 // ((b*H + h)*NKT + kt)
    const int kt = bid % NKT;
    const int h  = (bid / NKT) % Hh;
    const int b  = bid / (NKT * Hh);
    const int tid = threadIdx.x;
    const float* xb = x + (size_t)b * Nn * C3 + (size_t)kt * KVBLK * C3 + 768 + h * 64;
    u16t* Kdst = wsK + (size_t)bid * TILE_ELEMS;
    u16t* Vdst = wsV + (size_t)bid * TILE_ELEMS;

    #pragma unroll
    for (int rep = 0; rep < 4; ++rep) {
        int idx = tid + rep * 256;
        int m = idx >> 4;
        int d0 = (idx & 15) * 4;
        const float* src = &xb[(size_t)m * C3 + d0];
        float4 k4 = *(const float4*)src;
        ushort4 s4;
        s4.x = f2b(k4.x); s4.y = f2b(k4.y); s4.z = f2b(k4.z); s4.w = f2b(k4.w);
        *(ushort4*)&Kdst[swz(m, d0)] = s4;      // swz(m,d0) is 4-elem aligned
        float4 v4 = *(const float4*)(src + 768);
        Vt[swz(d0 + 0, m)] = f2b(v4.x);
        Vt[swz(d0 + 1, m)] = f2b(v4.y);
        Vt[swz(d0 + 2, m)] = f2b(v4.z);
        Vt[swz(d0 + 3, m)] = f2b(v4.w);
    }
    __syncthreads();
    // linear 8KB copy of the already-swizzled transposed tile
    const float4* s = (const float4*)Vt;
    float4* d = (float4*)Vdst;
    d[tid] = s[tid];
    d[tid + 256] = s[tid + 256];
}

// ---------------- pass 2: attention ----------------
__global__ __launch_bounds__(256, 3) void attn_kernel(
        const float* __restrict__ x,
        const float* __restrict__ tk,
        const float* __restrict__ tv,
        const u16t* __restrict__ wsK,
        const u16t* __restrict__ wsV,
        float* __restrict__ out) {
    __shared__ __align__(16) char smem[47872];
    u16t* Qlds  = (u16t*)smem;             // 8KB  [64][64] bf16 swizzled
    u16t* Klds  = (u16t*)(smem + 8192);    // 8KB  [64 keys][64 d] swizzled
    u16t* Vtlds = (u16t*)(smem + 16384);   // 8KB  [64 d][64 keys] swizzled
    u16t* Plds  = (u16t*)(smem + 24576);   // 8KB  per-wave [16 q][64 keys]
    float* qrel  = (float*)(smem + 32768); // [64][29]
    float* wdiag = (float*)(smem + 40192); // [64][27]
    float* lowL  = (float*)(smem + 47104); // [64]
    float* highL = (float*)(smem + 47360); // [64]
    float* Linv  = (float*)(smem + 47616); // [64]
    float* out2f = (float*)smem;           // reuse Qlds+Klds (16KB) after kv loop

    const int tid = threadIdx.x;
    const int bid = blockIdx.x;
    const int qt = bid % NQT;
    const int h  = (bid / NQT) % Hh;
    const int b  = bid / (NQT * Hh);
    const int lane = tid & 63;
    const int w = tid >> 6;
    const int g = lane >> 4;
    const int c = lane & 15;
    const int q0 = qt * QBLK;
    const float* xb = x + (size_t)b * Nn * C3;
    const size_t bh_tile0 = (size_t)((b * Hh + h) * NKT) * TILE_ELEMS;

    for (int i = tid; i < QBLK * 27; i += 256) wdiag[i] = 0.f;

    // ---- stage Q tile as bf16 (swizzled) ----
    #pragma unroll
    for (int rep = 0; rep < 4; ++rep) {
        int idx = tid + rep * 256;
        int row = idx >> 4;
        int d0 = (idx & 15) * 4;
        float4 v4 = *(const float4*)&xb[(size_t)(q0 + row) * C3 + h * 64 + d0];
        ushort4 s4;
        s4.x = f2b(v4.x); s4.y = f2b(v4.y); s4.z = f2b(v4.z); s4.w = f2b(v4.w);
        *(ushort4*)&Qlds[swz(row, d0)] = s4;
    }
    __syncthreads();

    // ---- qrel[q][t] = Q[q,:] . tk[t,:] ----
    for (int pid = tid; pid < QBLK * NT; pid += 256) {
        int q = pid / NT;
        int t = pid - q * NT;
        float s = 0.f;
        #pragma unroll
        for (int d0 = 0; d0 < 64; d0 += 8) {
            bf16x8 qv = *(const bf16x8*)&Qlds[swz(q, d0)];
            float4 t0 = *(const float4*)&tk[t * 64 + d0];
            float4 t1 = *(const float4*)&tk[t * 64 + d0 + 4];
            s += b2f((u16t)qv[0]) * t0.x + b2f((u16t)qv[1]) * t0.y
               + b2f((u16t)qv[2]) * t0.z + b2f((u16t)qv[3]) * t0.w
               + b2f((u16t)qv[4]) * t1.x + b2f((u16t)qv[5]) * t1.y
               + b2f((u16t)qv[6]) * t1.z + b2f((u16t)qv[7]) * t1.w;
        }
        qrel[q * NT + t] = s;
    }
    __syncthreads();

    // ---- per-wave Q fragments (A-operand): row = c, k = k0*32 + g*8 ----
    bf16x8 qfrag0 = *(const bf16x8*)&Qlds[swz(w * 16 + c, g * 8)];
    bf16x8 qfrag1 = *(const bf16x8*)&Qlds[swz(w * 16 + c, 32 + g * 8)];

    float qrl0[4], qrl28[4];
    #pragma unroll
    for (int r = 0; r < 4; ++r) {
        int ql = w * 16 + g * 4 + r;
        qrl0[r]  = qrel[ql * NT + 0];
        qrl28[r] = qrel[ql * NT + 28];
    }

    f32x4 of[4] = {};
    float lowA[4] = {0.f, 0.f, 0.f, 0.f};
    float highA[4] = {0.f, 0.f, 0.f, 0.f};
    const int qg_base = q0 + w * 16;

    for (int kt = 0; kt < NKT; ++kt) {
        const int kv0 = kt * KVBLK;
        __syncthreads();   // previous tile's LDS reads finished before overwrite
        // ---- stage K and Vt tiles: async bf16 copies, zero VALU conversion ----
        {
            const char* Ksrc = (const char*)(wsK + bh_tile0 + (size_t)kt * TILE_ELEMS);
            const char* Vsrc = (const char*)(wsV + bh_tile0 + (size_t)kt * TILE_ELEMS);
            #pragma unroll
            for (int i = 0; i < 2; ++i) {
                int off = w * 2048 + i * 1024;
                gl_lds16(Ksrc + off + lane * 16, (char*)Klds + off);
                gl_lds16(Vsrc + off + lane * 16, (char*)Vtlds + off);
            }
        }
        __syncthreads();   // compiler drains vmcnt before barrier

        // ---- S = Q.K^T per 16-col subtile, exp + bucket, P to LDS ----
        #pragma unroll
        for (int ct = 0; ct < 4; ++ct) {
            f32x4 s = {};
            {
                bf16x8 kf0 = *(const bf16x8*)&Klds[swz(ct * 16 + c, g * 8)];
                s = __builtin_amdgcn_mfma_f32_16x16x32_bf16(qfrag0, kf0, s, 0, 0, 0);
                bf16x8 kf1 = *(const bf16x8*)&Klds[swz(ct * 16 + c, 32 + g * 8)];
                s = __builtin_amdgcn_mfma_f32_16x16x32_bf16(qfrag1, kf1, s, 0, 0, 0);
            }
            const int key_g = kv0 + ct * 16 + c;
            const int dmax = kv0 + ct * 16 + 15 - qg_base;
            const int dmin = kv0 + ct * 16 - (qg_base + 15);
            float e[4];
            if (dmax <= -14) {              // whole subtile in bucket 0
                #pragma unroll
                for (int r = 0; r < 4; ++r) {
                    e[r] = __expf((s[r] + qrl0[r]) * SCALE);
                    lowA[r] += e[r];
                }
            } else if (dmin >= 14) {        // whole subtile in bucket 28
                #pragma unroll
                for (int r = 0; r < 4; ++r) {
                    e[r] = __expf((s[r] + qrl28[r]) * SCALE);
                    highA[r] += e[r];
                }
            } else {                        // diagonal band: generic path
                #pragma unroll
                for (int r = 0; r < 4; ++r) {
                    int ql = w * 16 + g * 4 + r;
                    int qg = q0 + ql;
                    int delta = key_g - qg;
                    int t = delta + 14;
                    t = t < 0 ? 0 : (t > 28 ? 28 : t);
                    float bias = qrel[ql * NT + t];
                    e[r] = __expf((s[r] + bias) * SCALE);
                    if (delta <= -14)      lowA[r] += e[r];
                    else if (delta >= 14)  highA[r] += e[r];
                    else                   wdiag[ql * 27 + delta + 13] = e[r];
                }
            }
            #pragma unroll
            for (int r = 0; r < 4; ++r)
                Plds[w * 1024 + swz(g * 4 + r, ct * 16 + c)] = f2b(e[r]);
        }
        asm volatile("s_waitcnt lgkmcnt(0)" ::: "memory");  // P writes visible wave-wide

        // ---- O += P.V ----
        #pragma unroll
        for (int k0 = 0; k0 < 2; ++k0) {
            bf16x8 pf = *(const bf16x8*)&Plds[w * 1024 + swz(c, k0 * 32 + g * 8)];
            #pragma unroll
            for (int dt = 0; dt < 4; ++dt) {
                bf16x8 vf = *(const bf16x8*)&Vtlds[swz(dt * 16 + c, k0 * 32 + g * 8)];
                of[dt] = __builtin_amdgcn_mfma_f32_16x16x32_bf16(pf, vf, of[dt], 0, 0, 0);
            }
        }
    }

    // ---- reduce low/high over the 16 lanes of each row group ----
    #pragma unroll
    for (int r = 0; r < 4; ++r) {
        float lo = lowA[r], hi = highA[r];
        #pragma unroll
        for (int m = 1; m < 16; m <<= 1) {
            lo += __shfl_xor(lo, m, 64);
            hi += __shfl_xor(hi, m, 64);
        }
        if (c == 0) {
            lowL[w * 16 + g * 4 + r]  = lo;
            highL[w * 16 + g * 4 + r] = hi;
        }
    }
    __syncthreads();

    // ---- out2[q][d] = sum_t w[t]*tv[t][d]; L = sum_t w[t] ----
    {
        const int q = tid >> 2;
        const int dp = (tid & 3) * 16;
        float lo = lowL[q], hi = highL[q];
        float wsum = lo + hi;
        float acc[16];
        const float* tva = &tv[dp];
        const float* tvb = &tv[28 * 64 + dp];
        #pragma unroll
        for (int i = 0; i < 16; ++i) acc[i] = lo * tva[i] + hi * tvb[i];
        for (int t = 1; t <= 27; ++t) {
            float wv = wdiag[q * 27 + (t - 1)];
            wsum += wv;
            const float* tvr = &tv[t * 64 + dp];
            #pragma unroll
            for (int i = 0; i < 16; ++i) acc[i] = fmaf(wv, tvr[i], acc[i]);
        }
        #pragma unroll
        for (int i = 0; i < 16; ++i) out2f[q * 64 + dp + i] = acc[i];
        if ((tid & 3) == 0) Linv[q] = 1.f / wsum;
    }
    __syncthreads();

    // ---- epilogue: out = (O + out2) / L ----
    #pragma unroll
    for (int dt = 0; dt < 4; ++dt) {
        #pragma unroll
        for (int r = 0; r < 4; ++r) {
            int ql = w * 16 + g * 4 + r;
            int d = dt * 16 + c;
            float val = (of[dt][r] + out2f[ql * 64 + d]) * Linv[ql];
            out[((size_t)b * Nn + q0 + ql) * 768 + h * 64 + d] = val;
        }
    }
}

extern "C" void kernel_launch(void* const* d_in, const int* in_sizes, int n_in,
                              void* d_out, int out_size, void* d_ws, size_t ws_size,
                              hipStream_t stream) {
    const float* x  = (const float*)d_in[0];
    const float* tk = (const float*)d_in[1];
    const float* tv = (const float*)d_in[2];
    float* out = (float*)d_out;
    // ws layout: K tiles then V tiles, each B*H*NKT*4096 bf16 = 12.58 MB (total 25.2 MB)
    u16t* wsK = (u16t*)d_ws;
    u16t* wsV = wsK + (size_t)Bb * Hh * NKT * TILE_ELEMS;
    preconv_kernel<<<dim3(Bb * Hh * NKT), dim3(256), 0, stream>>>(x, wsK, wsV);
    attn_kernel<<<dim3(Bb * Hh * NQT), dim3(256), 0, stream>>>(x, tk, tv, wsK, wsV, out);
}

// Round 3
// 167.004 us; speedup vs baseline: 1.1260x; 1.0225x over previous
//
#include <hip/hip_runtime.h>
#include <hip/hip_bf16.h>

#define Bb 8
#define Nn 1024
#define Hh 12
#define C3 2304
#define SCALE 0.125f
#define KK_E 0.1803368801f   // SCALE * log2(e)
#define QBLK 64
#define KVBLK 64
#define NT 29
#define NQT (Nn / QBLK)
#define NKT (Nn / KVBLK)
#define TILE_ELEMS 4096   // 64x64 bf16 tile

typedef short bf16x8 __attribute__((ext_vector_type(8)));
typedef float f32x4 __attribute__((ext_vector_type(4)));
typedef unsigned short u16t;

__device__ __forceinline__ float b2f(u16t v) {
    union { unsigned u; float f; } x; x.u = ((unsigned)v) << 16; return x.f;
}
__device__ __forceinline__ u16t f2b(float f) {
    union { float f; unsigned u; } x; x.f = f;
    unsigned r = x.u + 0x7fffu + ((x.u >> 16) & 1u);
    return (u16t)(r >> 16);
}
__device__ __forceinline__ unsigned pk2(float a, float b) {
    union { __hip_bfloat162 h; unsigned u; } cv;
    cv.h = __float22bfloat162_rn(make_float2(a, b));
    return cv.u;
}
// swizzled element index for row-major [rows][64] bf16 tiles (128B rows)
__device__ __forceinline__ int swz(int row, int col) {
    return (row * 64 + col) ^ ((row & 7) << 3);
}
// async global->LDS, 16B per lane; LDS dest is wave-uniform base (+lane*16 by HW)
__device__ __forceinline__ void gl_lds16(const void* g, void* l) {
    __builtin_amdgcn_global_load_lds(
        (const __attribute__((address_space(1))) unsigned int*)g,
        (__attribute__((address_space(3))) unsigned int*)l, 16, 0, 0);
}

// ---------------- pass 1: fp32 -> bf16, pre-swizzled K tiles + transposed V tiles ----
__global__ __launch_bounds__(256) void preconv_kernel(
        const float* __restrict__ x, u16t* __restrict__ wsK, u16t* __restrict__ wsV) {
    __shared__ __align__(16) u16t Vt[TILE_ELEMS];
    const int bid = blockIdx.x;                 // ((b*H + h)*NKT + kt)
    const int kt = bid % NKT;
    const int h  = (bid / NKT) % Hh;
    const int b  = bid / (NKT * Hh);
    const int tid = threadIdx.x;
    const float* xb = x + (size_t)b * Nn * C3 + (size_t)kt * KVBLK * C3 + 768 + h * 64;
    u16t* Kdst = wsK + (size_t)bid * TILE_ELEMS;
    u16t* Vdst = wsV + (size_t)bid * TILE_ELEMS;

    #pragma unroll
    for (int rep = 0; rep < 4; ++rep) {
        int idx = tid + rep * 256;
        int m = idx >> 4;
        int d0 = (idx & 15) * 4;
        const float* src = &xb[(size_t)m * C3 + d0];
        float4 k4 = *(const float4*)src;
        ushort4 s4;
        s4.x = f2b(k4.x); s4.y = f2b(k4.y); s4.z = f2b(k4.z); s4.w = f2b(k4.w);
        *(ushort4*)&Kdst[swz(m, d0)] = s4;      // swz(m,d0) is 4-elem aligned
        float4 v4 = *(const float4*)(src + 768);
        Vt[swz(d0 + 0, m)] = f2b(v4.x);
        Vt[swz(d0 + 1, m)] = f2b(v4.y);
        Vt[swz(d0 + 2, m)] = f2b(v4.z);
        Vt[swz(d0 + 3, m)] = f2b(v4.w);
    }
    __syncthreads();
    // linear 8KB copy of the already-swizzled transposed tile
    const float4* s = (const float4*)Vt;
    float4* d = (float4*)Vdst;
    d[tid] = s[tid];
    d[tid + 256] = s[tid + 256];
}

// ---------------- pass 2: attention ----------------
// LDS layout (52352 B total -> 3 blocks/CU):
//   [0,      8192)  Qlds (staging+frags) -> reused as per-wave PT (P^T tiles)
//   [8192,  24576)  Kbuf[2]  (double-buffered)   -> reused as out2f after loop
//   [24576, 40960)  Vbuf[2]  (double-buffered)
//   [40960, 44672)  qrel16 [64][29] bf16
//   [44672, 51584)  wdiag  [64][27] f32
//   [51584, 52352)  lowL/highL/Linv [64] f32 each
__global__ __launch_bounds__(256, 3) void attn_kernel(
        const float* __restrict__ x,
        const float* __restrict__ tk,
        const float* __restrict__ tv,
        const u16t* __restrict__ wsK,
        const u16t* __restrict__ wsV,
        float* __restrict__ out) {
    __shared__ __align__(16) char smem[52352];
    u16t* Qlds   = (u16t*)smem;
    u16t* PT     = (u16t*)smem;             // per-wave 2KB slabs, after qrel phase
    u16t* qrel16 = (u16t*)(smem + 40960);
    float* wdiag = (float*)(smem + 44672);
    float* lowL  = (float*)(smem + 51584);
    float* highL = (float*)(smem + 51840);
    float* Linv  = (float*)(smem + 52096);
    float* out2f = (float*)(smem + 8192);   // over Kbuf after kv loop

    const int tid = threadIdx.x;
    // bijective XCD swizzle: 16 q-blocks of one (b,h) land on one XCD
    const int work = (blockIdx.x & 7) * (Bb * Hh * NQT / 8) + (blockIdx.x >> 3);
    const int qt = work % NQT;
    const int h  = (work / NQT) % Hh;
    const int b  = work / (NQT * Hh);
    const int lane = tid & 63;
    const int w = tid >> 6;
    const int g = lane >> 4;
    const int c = lane & 15;
    const int q0 = qt * QBLK;
    const float* xb = x + (size_t)b * Nn * C3;
    const char* KsrcB = (const char*)(wsK + (size_t)((b * Hh + h) * NKT) * TILE_ELEMS);
    const char* VsrcB = (const char*)(wsV + (size_t)((b * Hh + h) * NKT) * TILE_ELEMS);

    auto stage = [&](int t, int bufsel) {
        const char* Ks = KsrcB + (size_t)t * 8192;
        const char* Vs = VsrcB + (size_t)t * 8192;
        char* Kd = smem + 8192 + bufsel * 8192;
        char* Vd = smem + 24576 + bufsel * 8192;
        #pragma unroll
        for (int i = 0; i < 2; ++i) {
            int off = w * 2048 + i * 1024;
            gl_lds16(Ks + off + lane * 16, Kd + off);
            gl_lds16(Vs + off + lane * 16, Vd + off);
        }
    };

    for (int i = tid; i < QBLK * 27; i += 256) wdiag[i] = 0.f;

    // ---- stage Q tile as bf16 (swizzled) + kick off tile-0 K/V ----
    #pragma unroll
    for (int rep = 0; rep < 4; ++rep) {
        int idx = tid + rep * 256;
        int row = idx >> 4;
        int d0 = (idx & 15) * 4;
        float4 v4 = *(const float4*)&xb[(size_t)(q0 + row) * C3 + h * 64 + d0];
        ushort4 s4;
        s4.x = f2b(v4.x); s4.y = f2b(v4.y); s4.z = f2b(v4.z); s4.w = f2b(v4.w);
        *(ushort4*)&Qlds[swz(row, d0)] = s4;
    }
    stage(0, 0);
    __syncthreads();

    // ---- qrel[q][t] = Q[q,:] . tk[t,:]  (bf16 table) ----
    for (int pid = tid; pid < QBLK * NT; pid += 256) {
        int q = pid / NT;
        int t = pid - q * NT;
        float s = 0.f;
        #pragma unroll
        for (int d0 = 0; d0 < 64; d0 += 8) {
            bf16x8 qv = *(const bf16x8*)&Qlds[swz(q, d0)];
            float4 t0 = *(const float4*)&tk[t * 64 + d0];
            float4 t1 = *(const float4*)&tk[t * 64 + d0 + 4];
            s += b2f((u16t)qv[0]) * t0.x + b2f((u16t)qv[1]) * t0.y
               + b2f((u16t)qv[2]) * t0.z + b2f((u16t)qv[3]) * t0.w
               + b2f((u16t)qv[4]) * t1.x + b2f((u16t)qv[5]) * t1.y
               + b2f((u16t)qv[6]) * t1.z + b2f((u16t)qv[7]) * t1.w;
        }
        qrel16[pid] = f2b(s);
    }
    __syncthreads();

    // ---- per-wave Q fragments (B-operand): col=q=w*16+c, k = g*8 (+32) ----
    bf16x8 qfrag0 = *(const bf16x8*)&Qlds[swz(w * 16 + c, g * 8)];
    bf16x8 qfrag1 = *(const bf16x8*)&Qlds[swz(w * 16 + c, 32 + g * 8)];
    const int qrow = w * 16 + c;                 // this lane's q (local)
    const float qb0  = b2f(qrel16[qrow * NT + 0])  * KK_E;
    const float qb28 = b2f(qrel16[qrow * NT + 28]) * KK_E;

    f32x4 of[4] = {};
    float lowA = 0.f, highA = 0.f;
    const int qg_base = q0 + w * 16;
    u16t* PTw = PT + w * 1024;

    auto tile_body = [&](int kt, int cursel) {
        if (kt + 1 < NKT) stage(kt + 1, cursel ^ 1);
        const u16t* K_ = (const u16t*)(smem + 8192 + cursel * 8192);
        const u16t* V_ = (const u16t*)(smem + 24576 + cursel * 8192);
        const int kv0 = kt * KVBLK;
        #pragma unroll
        for (int ct = 0; ct < 4; ++ct) {
            f32x4 s = {};
            {
                bf16x8 kf0 = *(const bf16x8*)&K_[swz(ct * 16 + c, g * 8)];
                s = __builtin_amdgcn_mfma_f32_16x16x32_bf16(kf0, qfrag0, s, 0, 0, 0);
                bf16x8 kf1 = *(const bf16x8*)&K_[swz(ct * 16 + c, 32 + g * 8)];
                s = __builtin_amdgcn_mfma_f32_16x16x32_bf16(kf1, qfrag1, s, 0, 0, 0);
            }
            // lane holds S^T[key = kv0+ct*16+g*4+r][q = q0+w*16+c]
            const int key_base = kv0 + ct * 16;
            const int dmax = key_base + 15 - qg_base;
            const int dmin = key_base - (qg_base + 15);
            float e[4];
            if (dmax <= -14) {              // whole subtile -> bucket 0
                #pragma unroll
                for (int r = 0; r < 4; ++r) {
                    e[r] = exp2f(fmaf(s[r], KK_E, qb0));
                    lowA += e[r];
                }
            } else if (dmin >= 14) {        // whole subtile -> bucket 28
                #pragma unroll
                for (int r = 0; r < 4; ++r) {
                    e[r] = exp2f(fmaf(s[r], KK_E, qb28));
                    highA += e[r];
                }
            } else {                        // diagonal band
                const int qg = qg_base + c;
                #pragma unroll
                for (int r = 0; r < 4; ++r) {
                    int key = key_base + g * 4 + r;
                    int delta = key - (q0 + qg - q0); // = key - (q0+qrow)
                    delta = key - (q0 + qrow);
                    int t = delta + 14;
                    t = t < 0 ? 0 : (t > 28 ? 28 : t);
                    float bias = b2f(qrel16[qrow * NT + t]) * KK_E;
                    e[r] = exp2f(fmaf(s[r], KK_E, bias));
                    if (delta <= -14)      lowA += e[r];
                    else if (delta >= 14)  highA += e[r];
                    else                   wdiag[qrow * 27 + delta + 13] = e[r];
                }
            }
            // pack 4 consecutive keys of row q -> one b64 write
            uint2 pw;
            pw.x = pk2(e[0], e[1]);
            pw.y = pk2(e[2], e[3]);
            *(uint2*)&PTw[swz(c, ct * 16 + g * 4)] = pw;
        }
        asm volatile("s_waitcnt lgkmcnt(0)" ::: "memory");  // PT visible wave-wide

        // ---- O^T += V^T . P^T ----
        #pragma unroll
        for (int k0 = 0; k0 < 2; ++k0) {
            bf16x8 pf = *(const bf16x8*)&PTw[swz(c, k0 * 32 + g * 8)];
            #pragma unroll
            for (int dt = 0; dt < 4; ++dt) {
                bf16x8 vf = *(const bf16x8*)&V_[swz(dt * 16 + c, k0 * 32 + g * 8)];
                of[dt] = __builtin_amdgcn_mfma_f32_16x16x32_bf16(vf, pf, of[dt], 0, 0, 0);
            }
        }
        __syncthreads();
    };

    for (int kt = 0; kt < NKT; kt += 2) {
        tile_body(kt, 0);
        tile_body(kt + 1, 1);
    }

    // ---- reduce low/high across the 4 g-groups (same q=c) ----
    lowA  += __shfl_xor(lowA, 16, 64);
    lowA  += __shfl_xor(lowA, 32, 64);
    highA += __shfl_xor(highA, 16, 64);
    highA += __shfl_xor(highA, 32, 64);
    if (g == 0) { lowL[qrow] = lowA; highL[qrow] = highA; }
    __syncthreads();

    // ---- out2[q][d] = sum_t w[t]*tv[t][d]; L = sum_t w[t] ----
    {
        const int q = tid >> 2;
        const int dp = (tid & 3) * 16;
        float lo = lowL[q], hi = highL[q];
        float wsum = lo + hi;
        float acc[16];
        const float* tva = &tv[dp];
        const float* tvb = &tv[28 * 64 + dp];
        #pragma unroll
        for (int i = 0; i < 16; ++i) acc[i] = lo * tva[i] + hi * tvb[i];
        for (int t = 1; t <= 27; ++t) {
            float wv = wdiag[q * 27 + (t - 1)];
            wsum += wv;
            const float* tvr = &tv[t * 64 + dp];
            #pragma unroll
            for (int i = 0; i < 16; ++i) acc[i] = fmaf(wv, tvr[i], acc[i]);
        }
        #pragma unroll
        for (int i = 0; i < 16; ++i) out2f[q * 64 + dp + i] = acc[i];
        if ((tid & 3) == 0) Linv[q] = 1.f / wsum;
    }
    __syncthreads();

    // ---- epilogue: out[q][d] = (O^T[d][q] + out2[q][d]) / L[q], float4 over d ----
    {
        const float linv = Linv[qrow];
        float* orow = &out[((size_t)b * Nn + q0 + qrow) * 768 + h * 64];
        #pragma unroll
        for (int dt = 0; dt < 4; ++dt) {
            const int d0 = dt * 16 + g * 4;
            const float* o2 = &out2f[qrow * 64 + d0];
            float4 o4;
            o4.x = (of[dt][0] + o2[0]) * linv;
            o4.y = (of[dt][1] + o2[1]) * linv;
            o4.z = (of[dt][2] + o2[2]) * linv;
            o4.w = (of[dt][3] + o2[3]) * linv;
            *(float4*)&orow[d0] = o4;
        }
    }
}

extern "C" void kernel_launch(void* const* d_in, const int* in_sizes, int n_in,
                              void* d_out, int out_size, void* d_ws, size_t ws_size,
                              hipStream_t stream) {
    const float* x  = (const float*)d_in[0];
    const float* tk = (const float*)d_in[1];
    const float* tv = (const float*)d_in[2];
    float* out = (float*)d_out;
    // ws layout: K tiles then V tiles, each B*H*NKT*4096 bf16 = 12.58 MB (total 25.2 MB)
    u16t* wsK = (u16t*)d_ws;
    u16t* wsV = wsK + (size_t)Bb * Hh * NKT * TILE_ELEMS;
    preconv_kernel<<<dim3(Bb * Hh * NKT), dim3(256), 0, stream>>>(x, wsK, wsV);
    attn_kernel<<<dim3(Bb * Hh * NQT), dim3(256), 0, stream>>>(x, tk, tv, wsK, wsV, out);
}